// Round 2
// baseline (2830.857 us; speedup 1.0000x reference)
//
#include <hip/hip_runtime.h>
#include <math.h>

#define BB 16
#define QQ 900
#define CC 91
#define TT 100
#define BT (BB * TT)        // 1600
#define NTHREADS 256

__device__ __forceinline__ unsigned ordkey(float f) {
    // monotone mapping: a < b  <=>  ordkey(a) < ordkey(b)  (no NaNs expected)
    unsigned u = __float_as_uint(f);
    return (u & 0x80000000u) ? ~u : (u | 0x80000000u);
}

__device__ __forceinline__ unsigned long long u64min(unsigned long long a, unsigned long long b) {
    return a < b ? a : b;
}

// ---------------------------------------------------------------------------
// Kernel 1: cost[b,q,j] for j in [0, B*T)
// ---------------------------------------------------------------------------
__global__ __launch_bounds__(NTHREADS) void cost_kernel(
    const float* __restrict__ logits,   // [B,Q,C]
    const float* __restrict__ pred,     // [B,Q,4] cxcywh
    const int*   __restrict__ tlab,     // [B*T]
    const float* __restrict__ tbox,     // [B*T,4] cxcywh
    float*       __restrict__ cost)     // [B,Q,B*T]
{
    const int bq = blockIdx.x;          // 0 .. B*Q-1
    __shared__ float sig[CC];

    const float* lg = logits + (size_t)bq * CC;
    for (int c = threadIdx.x; c < CC; c += NTHREADS) {
        float x = lg[c];
        sig[c] = 1.0f / (1.0f + expf(-x));   // matches np: 1/(1+exp(-x)) in fp32
    }

    // pred box (broadcast load — same address across all lanes)
    const float4 p = *(const float4*)(pred + (size_t)bq * 4);
    const float p_x0 = p.x - 0.5f * p.z;
    const float p_y0 = p.y - 0.5f * p.w;
    const float p_x1 = p.x + 0.5f * p.z;
    const float p_y1 = p.y + 0.5f * p.w;
    const float area1 = (p_x1 - p_x0) * (p_y1 - p_y0);

    __syncthreads();

    float* crow = cost + (size_t)bq * BT;
    for (int j = threadIdx.x; j < BT; j += NTHREADS) {
        float4 t = *(const float4*)(tbox + (size_t)j * 4);
        int id = tlab[j];
        float cclass = -sig[id];
        // L1 in cxcywh space, sequential sum order (((d0+d1)+d2)+d3)
        float cbbox = ((fabsf(p.x - t.x) + fabsf(p.y - t.y)) + fabsf(p.z - t.z)) + fabsf(p.w - t.w);

        float t_x0 = t.x - 0.5f * t.z, t_y0 = t.y - 0.5f * t.w;
        float t_x1 = t.x + 0.5f * t.z, t_y1 = t.y + 0.5f * t.w;
        float area2 = (t_x1 - t_x0) * (t_y1 - t_y0);

        float ltx = fmaxf(p_x0, t_x0), lty = fmaxf(p_y0, t_y0);
        float rbx = fminf(p_x1, t_x1), rby = fminf(p_y1, t_y1);
        float iw = fmaxf(rbx - ltx, 0.0f), ih = fmaxf(rby - lty, 0.0f);
        float inter = iw * ih;
        float uni = (area1 + area2) - inter;
        float iou = inter / uni;

        float ex0 = fminf(p_x0, t_x0), ey0 = fminf(p_y0, t_y0);
        float ex1 = fmaxf(p_x1, t_x1), ey1 = fmaxf(p_y1, t_y1);
        float ew = fmaxf(ex1 - ex0, 0.0f), eh = fmaxf(ey1 - ey0, 0.0f);
        float ae = ew * eh;
        float giou = iou - (ae - uni) / ae;

        // cost = cost_bbox + cost_class + cost_giou  (all weights 1.0)
        crow[j] = (cbbox + cclass) + (-giou);
    }
}

// ---------------------------------------------------------------------------
// Kernel 2: greedy matcher, one block per batch image.
// Maintains per-row (minval,mincol) cache in LDS; per step does a block
// argmin over rows (u64 key = ordered-bits<<32 | row -> exact numpy argmin
// tie-break) and rescans only rows whose cached min-col was removed.
// ---------------------------------------------------------------------------
__global__ __launch_bounds__(NTHREADS) void greedy_kernel(
    const float* __restrict__ cost,     // [B,Q,B*T]
    float*       __restrict__ rows_out, // [B,T] (as fp32)
    float*       __restrict__ cols_out) // [B,T] (as fp32)
{
    const int b = blockIdx.x;
    const float* cb = cost + (size_t)b * QQ * BT;

    __shared__ unsigned rowkey[QQ];     // ordered bits of current row min (0xFFFFFFFF = row removed)
    __shared__ int      rowcol[QQ];     // col of current row min
    __shared__ unsigned char colok[TT];
    __shared__ unsigned long long warpmin[NTHREADS / 64];
    __shared__ int s_c;

    const int tid = threadIdx.x;
    for (int c = tid; c < TT; c += NTHREADS) colok[c] = 1;

    // ---- initial row minima over cols [0, T) ----
    for (int r = tid; r < QQ; r += NTHREADS) {
        const float* row = cb + (size_t)r * BT;
        unsigned best = 0xFFFFFFFFu; int bc = 0;
        #pragma unroll
        for (int c4 = 0; c4 < TT / 4; ++c4) {
            float4 v = *(const float4*)(row + c4 * 4);
            unsigned k0 = ordkey(v.x), k1 = ordkey(v.y), k2 = ordkey(v.z), k3 = ordkey(v.w);
            if (k0 < best) { best = k0; bc = c4 * 4 + 0; }
            if (k1 < best) { best = k1; bc = c4 * 4 + 1; }
            if (k2 < best) { best = k2; bc = c4 * 4 + 2; }
            if (k3 < best) { best = k3; bc = c4 * 4 + 3; }
        }
        rowkey[r] = best; rowcol[r] = bc;
    }
    __syncthreads();

    for (int step = 0; step < TT; ++step) {
        // ---- block argmin over rows ----
        unsigned long long lb = ~0ULL;
        for (int r = tid; r < QQ; r += NTHREADS) {
            unsigned long long k = ((unsigned long long)rowkey[r] << 32) | (unsigned)r;
            lb = u64min(lb, k);
        }
        #pragma unroll
        for (int off = 32; off > 0; off >>= 1) {
            unsigned long long o = __shfl_down(lb, off, 64);
            lb = u64min(lb, o);
        }
        if ((tid & 63) == 0) warpmin[tid >> 6] = lb;
        __syncthreads();
        if (tid == 0) {
            unsigned long long m = u64min(u64min(warpmin[0], warpmin[1]),
                                          u64min(warpmin[2], warpmin[3]));
            int r = (int)(unsigned)(m & 0xFFFFFFFFu);
            int c = rowcol[r];
            s_c = c;
            rowkey[r] = 0xFFFFFFFFu;   // remove row
            colok[c] = 0;              // remove col
            rows_out[b * TT + step] = (float)r;
            cols_out[b * TT + step] = (float)c;
        }
        __syncthreads();
        const int cstar = s_c;

        // ---- rescan rows whose cached min-col was just removed ----
        for (int r = tid; r < QQ; r += NTHREADS) {
            if (rowkey[r] != 0xFFFFFFFFu && rowcol[r] == cstar) {
                const float* row = cb + (size_t)r * BT;
                unsigned best = 0xFFFFFFFFu; int bc = 0;
                #pragma unroll
                for (int c4 = 0; c4 < TT / 4; ++c4) {
                    float4 v = *(const float4*)(row + c4 * 4);
                    int c0 = c4 * 4;
                    unsigned k0 = colok[c0 + 0] ? ordkey(v.x) : 0xFFFFFFFFu;
                    unsigned k1 = colok[c0 + 1] ? ordkey(v.y) : 0xFFFFFFFFu;
                    unsigned k2 = colok[c0 + 2] ? ordkey(v.z) : 0xFFFFFFFFu;
                    unsigned k3 = colok[c0 + 3] ? ordkey(v.w) : 0xFFFFFFFFu;
                    if (k0 < best) { best = k0; bc = c0 + 0; }
                    if (k1 < best) { best = k1; bc = c0 + 1; }
                    if (k2 < best) { best = k2; bc = c0 + 2; }
                    if (k3 < best) { best = k3; bc = c0 + 3; }
                }
                rowkey[r] = best; rowcol[r] = bc;
            }
        }
        __syncthreads();
    }
}

extern "C" void kernel_launch(void* const* d_in, const int* in_sizes, int n_in,
                              void* d_out, int out_size, void* d_ws, size_t ws_size,
                              hipStream_t stream) {
    const float* logits = (const float*)d_in[0];   // [16,900,91]
    const float* pred   = (const float*)d_in[1];   // [16,900,4]
    const int*   tlab   = (const int*)d_in[2];     // [16,100]
    const float* tbox   = (const float*)d_in[3];   // [16,100,4]

    float* out = (float*)d_out;
    float* cost = out;                              // 16*900*1600 = 23,040,000
    float* rows = out + (size_t)BB * QQ * BT;       // 1600
    float* cols = rows + (size_t)BB * TT;           // 1600

    cost_kernel<<<BB * QQ, NTHREADS, 0, stream>>>(logits, pred, tlab, tbox, cost);
    greedy_kernel<<<BB, NTHREADS, 0, stream>>>(cost, rows, cols);
}